// Round 1
// baseline (99.712 us; speedup 1.0000x reference)
//
#include <hip/hip_runtime.h>

#define TPB 256
#define RPB 8                         // rows per tile
#define SEQ_L 2048
#define NCH 8                         // 256-wide j-chunks
#define NBATCH 8
#define NTILE 256                     // 8-row tiles per batch
#define NBLOCKS (NBATCH * NTILE)      // 2048
#define NWAVE (TPB / 64)

static constexpr float kBondTol  = 0.4f;
static constexpr float kClashTol = 1.5f;
static constexpr float kIdeal    = 3.8f;
static constexpr float kEps      = 1e-8f;
static constexpr float kThresh2  = 2.25f;   // 1.5^2: d2 >= this -> relu == 0
static constexpr float kFarBase  = 1.0e5f;  // masked-point sentinel base
static constexpr float kHugeD2   = 1.0e12f; // "not a pair" d2 sentinel

__device__ __forceinline__ float wred(float v) {
#pragma unroll
  for (int o = 32; o > 0; o >>= 1) v += __shfl_down(v, o, 64);
  return v;
}

// One 8-row tile per block (2048 blocks). LDS is xyz-only (24 KB) so 6 blocks
// co-reside per CU (24 waves/CU vs previous 16). Mask handling is geometric:
// masked points are moved to distinct far-away sentinels (spacing 4 > 1.5), so
// the clash accumulation needs NO mask weighting; the pair-mask denominator is
// analytic; bond/near-diagonal masks come from global (8 threads only).
// Final reduction is fused via a ticket counter: the last-arriving block
// reduces all 2048 partials deterministically and writes the output.
__global__ __launch_bounds__(TPB, 6) void viol_fused(
    const float* __restrict__ pos,    // [B, L, 3]
    const float* __restrict__ mask,   // [B, L]
    float4* __restrict__ partial,     // [NBLOCKS] in d_ws
    unsigned* __restrict__ counter,   // 4B in d_ws, memset to 0 each launch
    float* __restrict__ out) {
  __shared__ float sx[SEQ_L], sy[SEQ_L], sz[SEQ_L];   // 24 KB
  __shared__ float redm[NWAVE];
  __shared__ float red4[NWAVE][4];
  __shared__ int   sLast;

  const int b  = blockIdx.x & 7;      // batch -> XCD-pinned L2 reuse
  const int t  = blockIdx.x >> 3;     // tile 0..255
  const int i0 = t << 3;              // rows [i0, i0+8)
  const int k0 = t >> 5;              // first j-chunk (contains the diagonal)

  const float* pb = pos  + (size_t)b * SEQ_L * 3;
  const float* mb = mask + (size_t)b * SEQ_L;

  // ---- full-range mask sum; stage encoded xyz for chunks k0..7 only ----
  float mpart = 0.f;
#pragma unroll
  for (int it = 0; it < NCH; ++it) {
    const int idx = (int)threadIdx.x + (it << 8);
    const float m = mb[idx];
    mpart += m;
    if (it >= k0) {
      float x = pb[3 * idx + 0];
      float y = pb[3 * idx + 1];
      float z = pb[3 * idx + 2];
      if (m == 0.f) { x = kFarBase + 4.f * (float)idx; y = 0.f; z = 0.f; }
      sx[idx] = x; sy[idx] = y; sz[idx] = z;
    }
  }
  mpart = wred(mpart);
  const int wid  = threadIdx.x >> 6;
  const int lane = threadIdx.x & 63;
  if (lane == 0) redm[wid] = mpart;
  __syncthreads();
  const float msum = redm[0] + redm[1] + redm[2] + redm[3];

  float px[RPB], py[RPB], pz[RPB], accr[RPB];
#pragma unroll
  for (int q = 0; q < RPB; ++q) {     // broadcast reads (conflict-free)
    px[q] = sx[i0 + q]; py[q] = sy[i0 + q]; pz[q] = sz[i0 + q];
    accr[q] = 0.f;
  }

  // ---- boundary chunk (holds diagonal): j<=i killed via d2 sentinel ----
  {
    const int j = (int)threadIdx.x + (k0 << 8);
    const float xj = sx[j], yj = sy[j], zj = sz[j];
    float d2r[RPB];
#pragma unroll
    for (int q = 0; q < RPB; ++q) {
      const float dx = xj - px[q], dy = yj - py[q], dz = zj - pz[q];
      const float d2 = fmaf(dx, dx, fmaf(dy, dy, dz * dz));
      d2r[q] = (j > i0 + q) ? d2 : kHugeD2;   // strict upper triangle
    }
    float mv = d2r[0];
#pragma unroll
    for (int q = 1; q < RPB; ++q) mv = fminf(mv, d2r[q]);
    if (__ballot(mv < kThresh2) != 0ull) {
#pragma unroll
      for (int q = 0; q < RPB; ++q) {
        const float dist = __builtin_amdgcn_sqrtf(d2r[q] + kEps);
        accr[q] += fmaxf(kClashTol - dist, 0.f);
      }
    }
  }

  // ---- full chunks: every j there is > every tile row ----
  for (int k = k0 + 1; k < NCH; ++k) {
    const int j = (int)threadIdx.x + (k << 8);
    const float xj = sx[j], yj = sy[j], zj = sz[j];
    float d2r[RPB];
#pragma unroll
    for (int q = 0; q < RPB; ++q) {
      const float dx = xj - px[q], dy = yj - py[q], dz = zj - pz[q];
      d2r[q] = fmaf(dx, dx, fmaf(dy, dy, dz * dz));
    }
    float mv = d2r[0];
#pragma unroll
    for (int q = 1; q < RPB; ++q) mv = fminf(mv, d2r[q]);  // fuses to min3
    if (__ballot(mv < kThresh2) != 0ull) {
#pragma unroll
      for (int q = 0; q < RPB; ++q) {
        const float dist = __builtin_amdgcn_sqrtf(d2r[q] + kEps);
        accr[q] += fmaxf(kClashTol - dist, 0.f);
      }
    }
  }

  float cv = 0.f;
#pragma unroll
  for (int q = 0; q < RPB; ++q) cv += accr[q];

  // ---- near-diagonal correction (i < j <= i+2) + bond + analytic pm ----
  float bv = 0.f, bm = 0.f, pm = 0.f;
  if (threadIdx.x < 8) {
    const int i = i0 + (int)threadIdx.x;
    const float xi = sx[i], yi = sy[i], zi = sz[i];
    const int jhi = (i + 2 > SEQ_L - 1) ? SEQ_L - 1 : i + 2;
    float nv = 0.f;
    for (int j = i + 1; j <= jhi; ++j) {   // cancel exactly what main added
      const float dx = sx[j] - xi, dy = sy[j] - yi, dz = sz[j] - zi;
      const float dist = __builtin_amdgcn_sqrtf(dx*dx + dy*dy + dz*dz + kEps);
      nv += fmaxf(kClashTol - dist, 0.f);
    }
    cv -= nv;

    const float mi = mb[i];
    float nm = 0.f;                         // real masks, |i-j|<=2 incl. j==i
    const int jlo = (i - 2 < 0) ? 0 : i - 2;
    for (int j = jlo; j <= jhi; ++j) nm += mb[j];
    pm = mi * (msum - nm);                  // analytic pair-mask row sum

    if (i < SEQ_L - 1) {
      const float dx = sx[i+1] - xi, dy = sy[i+1] - yi, dz = sz[i+1] - zi;
      const float dist = __builtin_amdgcn_sqrtf(dx*dx + dy*dy + dz*dz + kEps);
      const float mj = mb[i + 1];
      bv = fmaxf(fabsf(dist - kIdeal) - kBondTol, 0.f) * mi * mj;
      bm = mi * mj;
    }
  }

  // ---- block reduction -> one float4 partial, then ticket ----
  bv = wred(bv); bm = wred(bm); cv = wred(cv); pm = wred(pm);
  if (lane == 0) {
    red4[wid][0] = bv; red4[wid][1] = bm;
    red4[wid][2] = cv; red4[wid][3] = pm;
  }
  __syncthreads();
  if (threadIdx.x == 0) {
    float tbv = 0.f, tbm = 0.f, tcv = 0.f, tpm = 0.f;
#pragma unroll
    for (int w = 0; w < NWAVE; ++w) {
      tbv += red4[w][0]; tbm += red4[w][1];
      tcv += red4[w][2]; tpm += red4[w][3];
    }
    partial[blockIdx.x] = make_float4(tbv, tbm, 2.f * tcv, tpm);
    __threadfence();                        // release: drain + L2 writeback
    const unsigned old = atomicAdd(counter, 1u);  // device-scope RMW
    sLast = (old == NBLOCKS - 1) ? 1 : 0;
  }
  __syncthreads();

  // ---- last-arriving block: deterministic final reduce + output ----
  if (sLast) {
    __threadfence();                        // acquire: invalidate stale lines
    float rbv = 0.f, rbm = 0.f, rcv = 0.f, rpm = 0.f;
    for (int i = (int)threadIdx.x; i < NBLOCKS; i += TPB) {
      float* p = (float*)(partial + i);     // agent-scope loads: cross-XCD safe
      rbv += __hip_atomic_load(p + 0, __ATOMIC_RELAXED, __HIP_MEMORY_SCOPE_AGENT);
      rbm += __hip_atomic_load(p + 1, __ATOMIC_RELAXED, __HIP_MEMORY_SCOPE_AGENT);
      rcv += __hip_atomic_load(p + 2, __ATOMIC_RELAXED, __HIP_MEMORY_SCOPE_AGENT);
      rpm += __hip_atomic_load(p + 3, __ATOMIC_RELAXED, __HIP_MEMORY_SCOPE_AGENT);
    }
    rbv = wred(rbv); rbm = wred(rbm); rcv = wred(rcv); rpm = wred(rpm);
    if (lane == 0) {
      red4[wid][0] = rbv; red4[wid][1] = rbm;
      red4[wid][2] = rcv; red4[wid][3] = rpm;
    }
    __syncthreads();
    if (threadIdx.x == 0) {
      float tbv = 0.f, tbm = 0.f, tcv = 0.f, tpm = 0.f;
#pragma unroll
      for (int w = 0; w < NWAVE; ++w) {
        tbv += red4[w][0]; tbm += red4[w][1];
        tcv += red4[w][2]; tpm += red4[w][3];
      }
      const float bond  = tbv / (tbm + kEps);
      const float clash = tcv / (tpm + kEps);
      out[0] = bond;
      out[1] = clash;
      out[2] = bond + clash;
    }
  }
}

extern "C" void kernel_launch(void* const* d_in, const int* in_sizes, int n_in,
                              void* d_out, int out_size, void* d_ws, size_t ws_size,
                              hipStream_t stream) {
  const float* pos  = (const float*)d_in[0];
  const float* mask = (const float*)d_in[1];
  float* out = (float*)d_out;
  float4* partial   = (float4*)d_ws;                       // 2048 * 16 B = 32 KB
  unsigned* counter = (unsigned*)((char*)d_ws + NBLOCKS * sizeof(float4));

  // ticket counter must be 0 each replay (workspace is re-poisoned between
  // iterations); a 4B memset node ahead of the kernel, graph-capture safe.
  hipMemsetAsync(counter, 0, sizeof(unsigned), stream);
  viol_fused<<<dim3(NBLOCKS), dim3(TPB), 0, stream>>>(pos, mask, partial,
                                                      counter, out);
}

// Round 2
// 64.020 us; speedup vs baseline: 1.5575x; 1.5575x over previous
//
#include <hip/hip_runtime.h>

#define TPB 256
#define RPB 8                           // rows per tile
#define SEQ_L 2048
#define CHUNK 256                       // j-chunk width = TPB
#define NCH (SEQ_L / CHUNK)             // 8
#define NBATCH 8
#define NPAIR 128                       // tile pairs (t, 255-t), t in 0..127
#define NBLOCKS (NBATCH * NPAIR)        // 1024
#define NWAVE (TPB / 64)                // 4

static constexpr float kBondTol  = 0.4f;
static constexpr float kClashTol = 1.5f;
static constexpr float kIdeal    = 3.8f;
static constexpr float kEps      = 1e-8f;
static constexpr float kThresh2  = 2.25f;   // 1.5^2: d2 >= this -> relu == 0
static constexpr float kFarBase  = 1.0e5f;  // masked-point sentinel base
static constexpr float kHugeD2   = 1.0e12f; // "not a pair" d2 sentinel

__device__ __forceinline__ float wred(float v) {
#pragma unroll
  for (int o = 32; o > 0; o >>= 1) v += __shfl_down(v, o, 64);
  return v;
}

// Round-0 proven skeleton (1024 paired-tile blocks {t, 255-t}, two plain
// kernels, no atomics/fences) + three latency attacks:
//  - fused dual-tile sweep: one pass over chunks k0A..7 serves BOTH tiles
//    (B active for k >= k0B, k0A+k0B == 7) -> avg 6.5 chunk reads vs 9,
//    identical & uniform VALU work per block;
//  - software prefetch of chunk k+1 while computing chunk k (ds_read
//    latency off the critical path);
//  - SoA xyz LDS (24 KB) + geometric mask sentinels: masked points are
//    relocated to spaced far-away positions (spacing 4 > 1.5), so the hot
//    loop needs NO mask weighting; pair-mask denominator is analytic.
__global__ __launch_bounds__(TPB, 4) void viol_main(
    const float* __restrict__ pos,    // [B, L, 3]
    const float* __restrict__ mask,   // [B, L]
    float4* __restrict__ partial) {   // [NBLOCKS]: (bv, bm, 2*cv_half, pm)
  __shared__ float sx[SEQ_L], sy[SEQ_L], sz[SEQ_L];   // 24 KB
  __shared__ float redm[NWAVE];
  __shared__ float red4[NWAVE][4];

  const int b   = blockIdx.x & 7;     // batch -> XCD-pinned L2 reuse
  const int t   = blockIdx.x >> 3;    // pair index 0..127
  const int i0A = t << 3;             // low tile rows  [i0A, i0A+8)
  const int i0B = (255 - t) << 3;     // high tile rows
  const int k0A = i0A >> 8;           // 0..3 (first chunk tile A needs)
  const int k0B = i0B >> 8;           // 4..7 (k0A + k0B == 7)

  const float* pb = pos  + (size_t)b * SEQ_L * 3;
  const float* mb = mask + (size_t)b * SEQ_L;

  // ---- stage chunks k0A..7 (all either tile needs); fuse mask-sum ----
  float mpart = 0.f;
#pragma unroll
  for (int it = 0; it < NCH; ++it) {
    const int idx = (int)threadIdx.x + (it << 8);
    const float m = mb[idx];
    mpart += m;
    if (it >= k0A) {
      float x = pb[3 * idx + 0];
      float y = pb[3 * idx + 1];
      float z = pb[3 * idx + 2];
      if (m == 0.f) { x = kFarBase + 4.f * (float)idx; y = 0.f; z = 0.f; }
      sx[idx] = x; sy[idx] = y; sz[idx] = z;
    }
  }
  mpart = wred(mpart);
  const int wid  = threadIdx.x >> 6;
  const int lane = threadIdx.x & 63;
  if (lane == 0) redm[wid] = mpart;
  __syncthreads();
  const float msum = redm[0] + redm[1] + redm[2] + redm[3];

  // ---- row registers for both tiles (broadcast reads, conflict-free) ----
  float pxA[RPB], pyA[RPB], pzA[RPB], accA[RPB];
  float pxB[RPB], pyB[RPB], pzB[RPB], accB[RPB];
#pragma unroll
  for (int q = 0; q < RPB; ++q) {
    pxA[q] = sx[i0A + q]; pyA[q] = sy[i0A + q]; pzA[q] = sz[i0A + q];
    pxB[q] = sx[i0B + q]; pyB[q] = sy[i0B + q]; pzB[q] = sz[i0B + q];
    accA[q] = 0.f; accB[q] = 0.f;
  }

  // ---- fused sweep over chunks k0A..7 with next-chunk prefetch ----
  {
    int jc = (int)threadIdx.x + (k0A << 8);
    float cx = sx[jc], cy = sy[jc], cz = sz[jc];
    for (int k = k0A; k < NCH; ++k) {
      const int kn = (k + 1 < NCH) ? k + 1 : k;       // harmless re-read at end
      const int jn = (int)threadIdx.x + (kn << 8);
      const float nx = sx[jn], ny = sy[jn], nz = sz[jn];
      const int j = (int)threadIdx.x + (k << 8);

      float d2r[RPB];
      // --- tile A: boundary (diagonal) only when k == k0A ---
#pragma unroll
      for (int q = 0; q < RPB; ++q) {
        const float dx = cx - pxA[q], dy = cy - pyA[q], dz = cz - pzA[q];
        d2r[q] = fmaf(dx, dx, fmaf(dy, dy, dz * dz));
      }
      if (k == k0A) {
#pragma unroll
        for (int q = 0; q < RPB; ++q)
          d2r[q] = (j > i0A + q) ? d2r[q] : kHugeD2;  // strict upper triangle
      }
      {
        float mv = d2r[0];
#pragma unroll
        for (int q = 1; q < RPB; ++q) mv = fminf(mv, d2r[q]); // fuses to min3
        if (__ballot(mv < kThresh2) != 0ull) {
#pragma unroll
          for (int q = 0; q < RPB; ++q) {
            const float dist = __builtin_amdgcn_sqrtf(d2r[q] + kEps);
            accA[q] += fmaxf(kClashTol - dist, 0.f);
          }
        }
      }
      // --- tile B: active for k >= k0B; boundary when k == k0B ---
      if (k >= k0B) {
#pragma unroll
        for (int q = 0; q < RPB; ++q) {
          const float dx = cx - pxB[q], dy = cy - pyB[q], dz = cz - pzB[q];
          d2r[q] = fmaf(dx, dx, fmaf(dy, dy, dz * dz));
        }
        if (k == k0B) {
#pragma unroll
          for (int q = 0; q < RPB; ++q)
            d2r[q] = (j > i0B + q) ? d2r[q] : kHugeD2;
        }
        float mv = d2r[0];
#pragma unroll
        for (int q = 1; q < RPB; ++q) mv = fminf(mv, d2r[q]);
        if (__ballot(mv < kThresh2) != 0ull) {
#pragma unroll
          for (int q = 0; q < RPB; ++q) {
            const float dist = __builtin_amdgcn_sqrtf(d2r[q] + kEps);
            accB[q] += fmaxf(kClashTol - dist, 0.f);
          }
        }
      }
      cx = nx; cy = ny; cz = nz;
    }
  }

  float cv = 0.f;
#pragma unroll
  for (int q = 0; q < RPB; ++q) cv += accA[q] + accB[q];

  // ---- near-diagonal correction (i < j <= i+2) + bond + analytic pm ----
  // 16 rows per block (2 tiles x 8): threads 0..15. Masks from global
  // (L2-hot); positions from LDS (sentinel-consistent with the main sweep).
  float bv = 0.f, bm = 0.f, pm = 0.f;
  if (threadIdx.x < 16) {
    const int i = ((threadIdx.x & 8) ? i0B : i0A) + (int)(threadIdx.x & 7);
    const float xi = sx[i], yi = sy[i], zi = sz[i];
    const int jhi = (i + 2 > SEQ_L - 1) ? SEQ_L - 1 : i + 2;
    float nv = 0.f;
    for (int j = i + 1; j <= jhi; ++j) {   // cancel exactly what main added
      const float dx = sx[j] - xi, dy = sy[j] - yi, dz = sz[j] - zi;
      const float dist = __builtin_amdgcn_sqrtf(dx*dx + dy*dy + dz*dz + kEps);
      nv += fmaxf(kClashTol - dist, 0.f);
    }
    cv -= nv;

    const float mi = mb[i];
    float nm = 0.f;                         // real masks, |i-j|<=2 incl. j==i
    const int jlo = (i - 2 < 0) ? 0 : i - 2;
    for (int j = jlo; j <= jhi; ++j) nm += mb[j];
    pm = mi * (msum - nm);                  // analytic pair-mask row sum

    if (i < SEQ_L - 1) {
      const float dx = sx[i+1] - xi, dy = sy[i+1] - yi, dz = sz[i+1] - zi;
      const float dist = __builtin_amdgcn_sqrtf(dx*dx + dy*dy + dz*dz + kEps);
      const float mj = mb[i + 1];
      bv = fmaxf(fabsf(dist - kIdeal) - kBondTol, 0.f) * mi * mj;
      bm = mi * mj;
    }
  }

  // ---- block reduction -> ONE plain float4 store per block (no atomics) ----
  bv = wred(bv); bm = wred(bm); cv = wred(cv); pm = wred(pm);
  if (lane == 0) {
    red4[wid][0] = bv; red4[wid][1] = bm;
    red4[wid][2] = cv; red4[wid][3] = pm;
  }
  __syncthreads();
  if (threadIdx.x == 0) {
    float tbv = 0.f, tbm = 0.f, tcv = 0.f, tpm = 0.f;
#pragma unroll
    for (int w = 0; w < NWAVE; ++w) {
      tbv += red4[w][0]; tbm += red4[w][1];
      tcv += red4[w][2]; tpm += red4[w][3];
    }
    // x2: upper triangle -> full ordered sum
    partial[blockIdx.x] = make_float4(tbv, tbm, 2.f * tcv, tpm);
  }
}

__global__ __launch_bounds__(TPB) void viol_reduce(
    const float4* __restrict__ partial, float* __restrict__ out) {
  __shared__ float red4[NWAVE][4];
  float bv = 0.f, bm = 0.f, cv = 0.f, pm = 0.f;
#pragma unroll
  for (int i = threadIdx.x; i < NBLOCKS; i += TPB) {
    float4 p = partial[i];
    bv += p.x; bm += p.y; cv += p.z; pm += p.w;
  }
  bv = wred(bv); bm = wred(bm); cv = wred(cv); pm = wred(pm);
  const int wid  = threadIdx.x >> 6;
  const int lane = threadIdx.x & 63;
  if (lane == 0) {
    red4[wid][0] = bv; red4[wid][1] = bm;
    red4[wid][2] = cv; red4[wid][3] = pm;
  }
  __syncthreads();
  if (threadIdx.x == 0) {
    float tbv = 0.f, tbm = 0.f, tcv = 0.f, tpm = 0.f;
#pragma unroll
    for (int w = 0; w < NWAVE; ++w) {
      tbv += red4[w][0]; tbm += red4[w][1];
      tcv += red4[w][2]; tpm += red4[w][3];
    }
    float bond  = tbv / (tbm + kEps);
    float clash = tcv / (tpm + kEps);
    out[0] = bond;
    out[1] = clash;
    out[2] = bond + clash;
  }
}

extern "C" void kernel_launch(void* const* d_in, const int* in_sizes, int n_in,
                              void* d_out, int out_size, void* d_ws, size_t ws_size,
                              hipStream_t stream) {
  const float* pos  = (const float*)d_in[0];
  const float* mask = (const float*)d_in[1];
  float* out = (float*)d_out;
  float4* partial = (float4*)d_ws;   // 1024 * 16 B = 16 KB scratch

  viol_main<<<dim3(NBLOCKS), dim3(TPB), 0, stream>>>(pos, mask, partial);
  viol_reduce<<<dim3(1), dim3(TPB), 0, stream>>>(partial, out);
}